// Round 1
// baseline (703.843 us; speedup 1.0000x reference)
//
#include <hip/hip_runtime.h>

#define N_NODES 100000
#define N_EDGES 1600000
#define IN_C    128
#define OUT_C   64

// ---------------- init: deg = 1 (self loop), agg = 0 ----------------
__global__ void init_kernel(float* __restrict__ deg, float* __restrict__ agg) {
    int i = blockIdx.x * blockDim.x + threadIdx.x;
    if (i < N_NODES * OUT_C) agg[i] = 0.f;
    if (i < N_NODES) deg[i] = 1.f;
}

// ---------------- degree: scatter-add ones over dst ----------------
__global__ void deg_kernel(const int* __restrict__ dst, float* __restrict__ deg) {
    int e = blockIdx.x * blockDim.x + threadIdx.x;
    if (e < N_EDGES) atomicAdd(&deg[dst[e]], 1.f);
}

// ---------------- dinv = rsqrt(deg) (deg >= 1 always) ----------------
__global__ void dinv_kernel(float* __restrict__ deg) {
    int n = blockIdx.x * blockDim.x + threadIdx.x;
    if (n < N_NODES) deg[n] = rsqrtf(deg[n]);
}

// ---------------- xw = x @ W   [N,128] @ [128,64] ----------------
// 4 nodes per 256-thread block; W staged in LDS (32 KiB).
__global__ void xw_kernel(const float* __restrict__ x, const float* __restrict__ W,
                          float* __restrict__ xw) {
    __shared__ float sW[IN_C * OUT_C];          // 32 KiB
    __shared__ float sx[4][IN_C];               // 2 KiB
    const int tid = threadIdx.x;
    for (int i = tid; i < IN_C * OUT_C; i += 256) sW[i] = W[i];
    const int nl = tid >> 6;                    // node within block
    const int c  = tid & 63;                    // output channel = lane
    const int n  = blockIdx.x * 4 + nl;
    for (int k = c; k < IN_C; k += 64)
        sx[nl][k] = (n < N_NODES) ? x[n * IN_C + k] : 0.f;
    __syncthreads();
    float acc = 0.f;
#pragma unroll 8
    for (int k = 0; k < IN_C; ++k)
        acc = fmaf(sx[nl][k], sW[k * OUT_C + c], acc);   // sW read: 2 lanes/bank = free
    if (n < N_NODES) xw[n * OUT_C + c] = acc;
}

// ---------------- aggregate: one wave per edge, lane = channel ----------------
__global__ void agg_kernel(const int* __restrict__ ei, const float* __restrict__ dinv,
                           const float* __restrict__ xw, float* __restrict__ agg) {
    long long idx = (long long)blockIdx.x * blockDim.x + threadIdx.x;
    int e = (int)(idx >> 6);
    int c = (int)(idx & 63);
    if (e >= N_EDGES) return;
    int s = ei[e];                // edge_index[0][e]  (broadcast load across wave)
    int d = ei[N_EDGES + e];      // edge_index[1][e]
    float norm = dinv[s] * dinv[d];
    atomicAdd(&agg[(long long)d * OUT_C + c], norm * xw[(long long)s * OUT_C + c]);
}

// ---------------- node epilogue: h = relu(agg + dinv^2*xw + b); pq = [h@Wc_lo, h@Wc_hi]
__global__ void node_kernel(const float* __restrict__ dinv, const float* __restrict__ xw,
                            const float* __restrict__ agg, const float* __restrict__ b,
                            const float* __restrict__ Wc, float4* __restrict__ pq) {
    int idx = blockIdx.x * blockDim.x + threadIdx.x;
    int n = idx >> 6;
    int c = idx & 63;
    if (n >= N_NODES) return;
    float di = dinv[n];
    float h = agg[n * OUT_C + c] + di * di * xw[n * OUT_C + c] + b[c];
    h = fmaxf(h, 0.f);
    // Wc is [128, 2] row-major; rows 0..63 multiply the src half, 64..127 the dst half
    float p0 = h * Wc[2 * c + 0];
    float p1 = h * Wc[2 * c + 1];
    float q0 = h * Wc[2 * (OUT_C + c) + 0];
    float q1 = h * Wc[2 * (OUT_C + c) + 1];
#pragma unroll
    for (int off = 32; off; off >>= 1) {       // wave64 butterfly reduce
        p0 += __shfl_down(p0, off);
        p1 += __shfl_down(p1, off);
        q0 += __shfl_down(q0, off);
        q1 += __shfl_down(q1, off);
    }
    if (c == 0) pq[n] = make_float4(p0, p1, q0, q1);
}

// ---------------- edge outputs: out[e] = p[src] + q[dst] + bc ----------------
__global__ void edge_kernel(const int* __restrict__ ei, const int* __restrict__ nei,
                            const float4* __restrict__ pq, const float* __restrict__ bc,
                            float2* __restrict__ out) {
    int e = blockIdx.x * blockDim.x + threadIdx.x;
    if (e >= 2 * N_EDGES) return;
    int s, d;
    if (e < N_EDGES) { s = ei[e];            d = ei[N_EDGES + e]; }
    else             { s = nei[e - N_EDGES]; d = nei[2 * N_EDGES - N_EDGES + (e - N_EDGES)]; }
    float4 ps = pq[s];
    float4 qd = pq[d];
    out[e] = make_float2(ps.x + qd.z + bc[0], ps.y + qd.w + bc[1]);
}

extern "C" void kernel_launch(void* const* d_in, const int* in_sizes, int n_in,
                              void* d_out, int out_size, void* d_ws, size_t ws_size,
                              hipStream_t stream) {
    const float* x   = (const float*)d_in[0];   // [N,128]
    const int*   ei  = (const int*)  d_in[1];   // [2,E]
    const int*   nei = (const int*)  d_in[2];   // [2,E]
    const float* W   = (const float*)d_in[3];   // [128,64]
    const float* b   = (const float*)d_in[4];   // [64]
    const float* Wc  = (const float*)d_in[5];   // [128,2]
    const float* bc  = (const float*)d_in[6];   // [2]
    float* out = (float*)d_out;                 // [2E,2]

    // workspace layout (floats), 16B-aligned offsets
    float* ws  = (float*)d_ws;
    float* deg = ws;                    // N      (becomes dinv in place)
    float* xw  = ws + 100352;           // N*64
    float* agg = xw + (size_t)N_NODES * OUT_C;
    float* pq  = agg + (size_t)N_NODES * OUT_C; // N*4 (float4 per node)

    const int B = 256;
    // 1) init deg=1, agg=0
    init_kernel<<<(N_NODES * OUT_C + B - 1) / B, B, 0, stream>>>(deg, agg);
    // 2) in-degree (+ self loop already in init)
    deg_kernel<<<(N_EDGES + B - 1) / B, B, 0, stream>>>(ei + N_EDGES, deg);
    // 3) dinv
    dinv_kernel<<<(N_NODES + B - 1) / B, B, 0, stream>>>(deg);
    // 4) xw = x @ W
    xw_kernel<<<(N_NODES + 3) / 4, B, 0, stream>>>(x, W, xw);
    // 5) scatter-add aggregation (one wave per edge)
    {
        long long threads = (long long)N_EDGES * 64;
        agg_kernel<<<(int)((threads + B - 1) / B), B, 0, stream>>>(ei, deg, xw, agg);
    }
    // 6) node epilogue -> pq table (1.6 MB)
    node_kernel<<<(N_NODES * 64 + B - 1) / B, B, 0, stream>>>(deg, xw, agg, b, Wc,
                                                              (float4*)pq);
    // 7) edge outputs
    edge_kernel<<<(2 * N_EDGES + B - 1) / B, B, 0, stream>>>(ei, nei, (const float4*)pq,
                                                             bc, (float2*)out);
}

// Round 2
// 467.230 us; speedup vs baseline: 1.5064x; 1.5064x over previous
//
#include <hip/hip_runtime.h>

#define N_NODES 100000
#define N_EDGES 1600000
#define IN_C    128
#define OUT_C   64

#define SCAN_CHUNK 1024
#define NB_SCAN ((N_NODES + SCAN_CHUNK - 1) / SCAN_CHUNK)   // 98

// ---------------- zero in-degree counters ----------------
__global__ void zero_kernel(int* __restrict__ count) {
    int i = blockIdx.x * blockDim.x + threadIdx.x;
    if (i < N_NODES) count[i] = 0;
}

// ---------------- in-degree count (int atomics) ----------------
__global__ void count_kernel(const int* __restrict__ dst, int* __restrict__ count) {
    int e = blockIdx.x * blockDim.x + threadIdx.x;
    if (e < N_EDGES) atomicAdd(&count[dst[e]], 1);
}

// ---------------- scan stage 1: per-1024-chunk exclusive scan + block sums ----
__global__ void scan1_kernel(const int* __restrict__ count, int* __restrict__ rowptr,
                             int* __restrict__ bsum) {
    __shared__ int sc[256];
    const int t = threadIdx.x, b = blockIdx.x;
    const int base = b * SCAN_CHUNK + t * 4;
    int v0 = 0, v1 = 0, v2 = 0, v3 = 0;
    if (base + 3 < N_NODES) {
        int4 v = *(const int4*)&count[base];
        v0 = v.x; v1 = v.y; v2 = v.z; v3 = v.w;
    } else {
        if (base + 0 < N_NODES) v0 = count[base + 0];
        if (base + 1 < N_NODES) v1 = count[base + 1];
        if (base + 2 < N_NODES) v2 = count[base + 2];
        if (base + 3 < N_NODES) v3 = count[base + 3];
    }
    sc[t] = v0 + v1 + v2 + v3;
    __syncthreads();
    for (int off = 1; off < 256; off <<= 1) {
        int u = (t >= off) ? sc[t - off] : 0;
        __syncthreads();
        sc[t] += u;
        __syncthreads();
    }
    int excl = (t == 0) ? 0 : sc[t - 1];
    if (t == 255) bsum[b] = sc[255];
    if (base + 0 < N_NODES) rowptr[base + 0] = excl; excl += v0;
    if (base + 1 < N_NODES) rowptr[base + 1] = excl; excl += v1;
    if (base + 2 < N_NODES) rowptr[base + 2] = excl; excl += v2;
    if (base + 3 < N_NODES) rowptr[base + 3] = excl;
}

// ---------------- scan stage 2: exclusive scan of the 98 block sums ----------
__global__ void scan2_kernel(int* __restrict__ bsum) {
    __shared__ int sc[128];
    const int t = threadIdx.x;                   // 128 threads
    int v = (t < NB_SCAN) ? bsum[t] : 0;
    sc[t] = v;
    __syncthreads();
    for (int off = 1; off < 128; off <<= 1) {
        int u = (t >= off) ? sc[t - off] : 0;
        __syncthreads();
        sc[t] += u;
        __syncthreads();
    }
    if (t < NB_SCAN) bsum[t] = sc[t] - v;        // exclusive
}

// ---------------- scan stage 3: add offsets; init cursor & dinv --------------
__global__ void scan3_kernel(const int* __restrict__ count, int* __restrict__ rowptr,
                             int* __restrict__ cursor, float* __restrict__ dinv,
                             const int* __restrict__ bsum) {
    const int t = threadIdx.x, b = blockIdx.x;
    const int base = b * SCAN_CHUNK + t * 4;
    const int off = bsum[b];
#pragma unroll
    for (int j = 0; j < 4; ++j) {
        int idx = base + j;
        if (idx < N_NODES) {
            int rp = rowptr[idx] + off;
            rowptr[idx] = rp;
            cursor[idx] = rp;
            dinv[idx]   = rsqrtf((float)count[idx] + 1.0f);   // +1 self-loop
        }
    }
    if (b == 0 && t == 0) rowptr[N_NODES] = N_EDGES;
}

// ---------------- scatter edges into CSR (int atomics on cursors) ------------
__global__ void scatter_kernel(const int* __restrict__ ei, int* __restrict__ cursor,
                               int* __restrict__ srcs) {
    int e = blockIdx.x * blockDim.x + threadIdx.x;
    if (e >= N_EDGES) return;
    int s = ei[e];
    int d = ei[N_EDGES + e];
    int pos = atomicAdd(&cursor[d], 1);
    srcs[pos] = s;
}

// ---------------- xw = x @ W : 16 nodes/block, thread = (node, 4 channels) ---
#define XW_NODES 16
#define SX_STRIDE 132     // pad 128 -> 132 to break 4-way bank conflict
__global__ __launch_bounds__(256) void xw_kernel(const float* __restrict__ x,
                                                 const float* __restrict__ W,
                                                 float* __restrict__ xw) {
    __shared__ float sW[IN_C * OUT_C];            // 32 KiB
    __shared__ float sx[XW_NODES * SX_STRIDE];    // 8.25 KiB
    const int t = threadIdx.x;
    const int n0 = blockIdx.x * XW_NODES;
    const float4* W4 = (const float4*)W;
    float4* sW4 = (float4*)sW;
    for (int i = t; i < IN_C * OUT_C / 4; i += 256) sW4[i] = W4[i];
    for (int i = t; i < XW_NODES * IN_C; i += 256) {
        int r = i >> 7, k = i & 127;
        int n = n0 + r;
        sx[r * SX_STRIDE + k] = (n < N_NODES) ? x[n * IN_C + k] : 0.f;
    }
    __syncthreads();
    const int r  = t >> 4;            // node in tile
    const int cq = (t & 15) << 2;     // channel quad base
    float4 acc = make_float4(0.f, 0.f, 0.f, 0.f);
#pragma unroll 16
    for (int k = 0; k < IN_C; ++k) {
        float  xv = sx[r * SX_STRIDE + k];
        float4 wv = *(const float4*)&sW[(k << 6) + cq];
        acc.x = fmaf(xv, wv.x, acc.x);
        acc.y = fmaf(xv, wv.y, acc.y);
        acc.z = fmaf(xv, wv.z, acc.z);
        acc.w = fmaf(xv, wv.w, acc.w);
    }
    int n = n0 + r;
    if (n < N_NODES) *(float4*)&xw[n * OUT_C + cq] = acc;
}

// ---------------- fused pull-aggregate + epilogue: wave per node -------------
// h = relu(dinv[n]*(sum_s dinv[s]*xw[s]) + dinv[n]^2*xw[n] + b)
// pq[n] = (h@Wc_src + bc, h@Wc_dst)
__global__ __launch_bounds__(256) void aggnode_kernel(
    const int* __restrict__ rowptr, const int* __restrict__ srcs,
    const float* __restrict__ dinv, const float* __restrict__ xw,
    const float* __restrict__ b, const float* __restrict__ Wc,
    const float* __restrict__ bc, float4* __restrict__ pq) {
    const int lane = threadIdx.x & 63;
    const int node = blockIdx.x * 4 + (threadIdx.x >> 6);
    if (node >= N_NODES) return;
    const int beg = rowptr[node], end = rowptr[node + 1];
    const int c = lane;
    float acc = 0.f;
    int i = beg;
    while (i < end) {
        int cnt = end - i;
        if (cnt > 64) cnt = 64;
        int   sv = 0;
        float wv = 0.f;
        if (lane < cnt) { sv = srcs[i + lane]; wv = dinv[sv]; }
        int j = 0;
        for (; j + 3 < cnt; j += 4) {   // 4 independent gathers in flight
            int   s0 = __shfl(sv, j),     s1 = __shfl(sv, j + 1);
            int   s2 = __shfl(sv, j + 2), s3 = __shfl(sv, j + 3);
            float w0 = __shfl(wv, j),     w1 = __shfl(wv, j + 1);
            float w2 = __shfl(wv, j + 2), w3 = __shfl(wv, j + 3);
            float x0 = xw[s0 * OUT_C + c], x1 = xw[s1 * OUT_C + c];
            float x2 = xw[s2 * OUT_C + c], x3 = xw[s3 * OUT_C + c];
            acc = fmaf(w0, x0, acc); acc = fmaf(w1, x1, acc);
            acc = fmaf(w2, x2, acc); acc = fmaf(w3, x3, acc);
        }
        for (; j < cnt; ++j) {
            int s = __shfl(sv, j);
            float w = __shfl(wv, j);
            acc = fmaf(w, xw[s * OUT_C + c], acc);
        }
        i += cnt;
    }
    float di = dinv[node];
    float h = fmaf(di, acc, di * di * xw[node * OUT_C + c]) + b[c];
    h = fmaxf(h, 0.f);
    float p0 = h * Wc[2 * c + 0],           p1 = h * Wc[2 * c + 1];
    float q0 = h * Wc[2 * (OUT_C + c) + 0], q1 = h * Wc[2 * (OUT_C + c) + 1];
#pragma unroll
    for (int off = 32; off; off >>= 1) {
        p0 += __shfl_down(p0, off); p1 += __shfl_down(p1, off);
        q0 += __shfl_down(q0, off); q1 += __shfl_down(q1, off);
    }
    if (lane == 0) pq[node] = make_float4(p0 + bc[0], p1 + bc[1], q0, q1);
}

// ---------------- edge outputs: out[e] = p[src] + q[dst] (bc already in p) ---
__global__ void edge_kernel(const int* __restrict__ ei, const int* __restrict__ nei,
                            const float4* __restrict__ pq, float4* __restrict__ out4) {
    int idx = blockIdx.x * blockDim.x + threadIdx.x;   // handles 2 edges
    if (idx >= N_EDGES) return;                        // 2E edges total / 2
    int e2 = idx * 2;
    int2 ss, dd;
    if (e2 < N_EDGES) {
        ss = *(const int2*)&ei[e2];
        dd = *(const int2*)&ei[N_EDGES + e2];
    } else {
        int f = e2 - N_EDGES;
        ss = *(const int2*)&nei[f];
        dd = *(const int2*)&nei[N_EDGES + f];
    }
    float4 pa = pq[ss.x], qa = pq[dd.x];
    float4 pb = pq[ss.y], qb = pq[dd.y];
    out4[idx] = make_float4(pa.x + qa.z, pa.y + qa.w, pb.x + qb.z, pb.y + qb.w);
}

extern "C" void kernel_launch(void* const* d_in, const int* in_sizes, int n_in,
                              void* d_out, int out_size, void* d_ws, size_t ws_size,
                              hipStream_t stream) {
    const float* x   = (const float*)d_in[0];   // [N,128]
    const int*   ei  = (const int*)  d_in[1];   // [2,E]
    const int*   nei = (const int*)  d_in[2];   // [2,E]
    const float* W   = (const float*)d_in[3];   // [128,64]
    const float* b   = (const float*)d_in[4];   // [64]
    const float* Wc  = (const float*)d_in[5];   // [128,2]
    const float* bc  = (const float*)d_in[6];   // [2]

    // workspace layout (int/float are both 4 B; offsets 256B-aligned)
    int*   wsI    = (int*)d_ws;
    int*   count  = wsI;                 // N
    int*   rowptr = wsI + 100352;        // N+1
    int*   cursor = wsI + 200704;        // N
    int*   bsum   = wsI + 301056;        // NB_SCAN (98)
    int*   srcs   = wsI + 301568;        // E
    float* dinv   = (float*)(wsI + 1901568);   // N
    float* xw     = (float*)(wsI + 2001920);   // N*64
    float* pq     = (float*)(wsI + 8401920);   // N*4 (float4)

    const int B = 256;
    zero_kernel<<<(N_NODES + B - 1) / B, B, 0, stream>>>(count);
    count_kernel<<<(N_EDGES + B - 1) / B, B, 0, stream>>>(ei + N_EDGES, count);
    scan1_kernel<<<NB_SCAN, B, 0, stream>>>(count, rowptr, bsum);
    scan2_kernel<<<1, 128, 0, stream>>>(bsum);
    scan3_kernel<<<NB_SCAN, B, 0, stream>>>(count, rowptr, cursor, dinv, bsum);
    scatter_kernel<<<(N_EDGES + B - 1) / B, B, 0, stream>>>(ei, cursor, srcs);
    xw_kernel<<<(N_NODES + XW_NODES - 1) / XW_NODES, B, 0, stream>>>(x, W, xw);
    aggnode_kernel<<<(N_NODES + 3) / 4, B, 0, stream>>>(rowptr, srcs, dinv, xw, b, Wc,
                                                        bc, (float4*)pq);
    edge_kernel<<<(N_EDGES + B - 1) / B, B, 0, stream>>>(ei, nei, (const float4*)pq,
                                                         (float4*)d_out);
}